// Round 1
// baseline (1165.462 us; speedup 1.0000x reference)
//
#include <hip/hip_runtime.h>
#include <math.h>

// GCN 2-layer + mean-pool + sigmoid for MI355X.
// Factorized form: out[d] = dinv[d] * (sum_{s->d} g[s] + g[d]),  g = dinv * (h@W)
// (self-loop term folds in because dinv[d]^2*hw[d] = dinv[d]*g[d]).

#define TPB 256

__global__ void count_deg_kernel(const int* __restrict__ dst, int E, int* __restrict__ deg) {
    int e = blockIdx.x * blockDim.x + threadIdx.x;
    if (e < E) atomicAdd(&deg[dst[e]], 1);
}

// per node: dinv = rsqrt(deg+1);  g1[n][f] = dinv * sum_i x[n][i]*W1[i][f]
__global__ void node_prep_kernel(const float* __restrict__ x, const float* __restrict__ W1,
                                 const int* __restrict__ deg, float* __restrict__ dinv,
                                 float* __restrict__ g1, int N) {
    __shared__ float sW[7 * 16];
    int t = threadIdx.x;
    if (t < 7 * 16) sW[t] = W1[t];
    __syncthreads();
    int n = blockIdx.x * blockDim.x + t;
    if (n >= N) return;
    float di = rsqrtf((float)deg[n] + 1.0f);
    dinv[n] = di;
    float xi[7];
#pragma unroll
    for (int i = 0; i < 7; ++i) xi[i] = x[n * 7 + i];
#pragma unroll
    for (int f = 0; f < 16; ++f) {
        float acc = 0.f;
#pragma unroll
        for (int i = 0; i < 7; ++i) acc = fmaf(xi[i], sW[i * 16 + f], acc);
        g1[n * 16 + f] = di * acc;
    }
}

// one thread per (edge, feature): 16 lanes share an edge -> coalesced 64B gather
__global__ void scatter1_kernel(const int* __restrict__ src, const int* __restrict__ dst,
                                const float* __restrict__ g1, float* __restrict__ acc1,
                                long long total) {
    long long idx = (long long)blockIdx.x * blockDim.x + threadIdx.x;
    if (idx >= total) return;
    int e = (int)(idx >> 4);
    int f = (int)(idx & 15);
    int s = src[e];
    int d = dst[e];
    atomicAdd(&acc1[(long long)d * 16 + f], g1[(long long)s * 16 + f]);
}

// h1 = relu(dinv*(acc1+g1)+b1); y = h1 @ W2; g2 = dinv*y   (h1 never stored)
__global__ void layer1_finish_kernel(const float* __restrict__ acc1, const float* __restrict__ g1,
                                     const float* __restrict__ dinv, const float* __restrict__ b1,
                                     const float* __restrict__ W2, float* __restrict__ g2, int N) {
    __shared__ float sb[16], sw2[16];
    int t = threadIdx.x;
    if (t < 16) { sb[t] = b1[t]; sw2[t] = W2[t]; }
    __syncthreads();
    int n = blockIdx.x * blockDim.x + t;
    if (n >= N) return;
    float di = dinv[n];
    float y = 0.f;
#pragma unroll
    for (int f = 0; f < 16; ++f) {
        float h = di * (acc1[(long long)n * 16 + f] + g1[(long long)n * 16 + f]) + sb[f];
        h = fmaxf(h, 0.f);
        y = fmaf(h, sw2[f], y);
    }
    g2[n] = di * y;
}

__global__ void scatter2_kernel(const int* __restrict__ src, const int* __restrict__ dst,
                                const float* __restrict__ g2, float* __restrict__ acc2, int E) {
    int e = blockIdx.x * blockDim.x + threadIdx.x;
    if (e < E) atomicAdd(&acc2[dst[e]], g2[src[e]]);
}

// h2 = dinv*(acc2+g2)+b2 ; pool into 64 per-block shared bins; flush with atomics
__global__ void pool_kernel(const float* __restrict__ acc2, const float* __restrict__ g2,
                            const float* __restrict__ dinv, const float* __restrict__ b2,
                            const int* __restrict__ batch, float* __restrict__ sums,
                            float* __restrict__ cnts, int N) {
    __shared__ float ssum[64];
    __shared__ float scnt[64];
    int t = threadIdx.x;
    if (t < 64) { ssum[t] = 0.f; scnt[t] = 0.f; }
    __syncthreads();
    int n = blockIdx.x * blockDim.x + t;
    if (n < N) {
        float di = dinv[n];
        float h2 = di * (acc2[n] + g2[n]) + b2[0];
        int g = batch[n];
        atomicAdd(&ssum[g], h2);
        atomicAdd(&scnt[g], 1.0f);
    }
    __syncthreads();
    if (t < 64) {
        if (scnt[t] != 0.f) {
            atomicAdd(&sums[t], ssum[t]);
            atomicAdd(&cnts[t], scnt[t]);
        }
    }
}

__global__ void finalize_kernel(const float* __restrict__ sums, const float* __restrict__ cnts,
                                float* __restrict__ out, int G) {
    int g = blockIdx.x * blockDim.x + threadIdx.x;
    if (g < G) {
        float m = sums[g] / fmaxf(cnts[g], 1.0f);
        out[g] = 1.0f / (1.0f + expf(-m));
    }
}

extern "C" void kernel_launch(void* const* d_in, const int* in_sizes, int n_in,
                              void* d_out, int out_size, void* d_ws, size_t ws_size,
                              hipStream_t stream) {
    const float* x  = (const float*)d_in[0];
    const float* W1 = (const float*)d_in[1];
    const float* b1 = (const float*)d_in[2];
    const float* W2 = (const float*)d_in[3];
    const float* b2 = (const float*)d_in[4];
    const int* ei   = (const int*)d_in[5];
    const int* batch = (const int*)d_in[6];

    const int N = in_sizes[0] / 7;
    const int E = in_sizes[5] / 2;
    const int G = out_size;
    const int* src = ei;
    const int* dst = ei + E;

    // workspace layout (256B-aligned)
    char* ws = (char*)d_ws;
    size_t off = 0;
    auto walloc = [&](size_t bytes) -> void* {
        void* p = ws + off;
        off += (bytes + 255) & ~(size_t)255;
        return p;
    };
    float* dinv = (float*)walloc((size_t)N * 4);
    int*   deg  = (int*)  walloc((size_t)N * 4);
    float* g1   = (float*)walloc((size_t)N * 16 * 4);
    float* acc1 = (float*)walloc((size_t)N * 16 * 4);
    float* g2   = (float*)walloc((size_t)N * 4);
    float* acc2 = (float*)walloc((size_t)N * 4);
    float* sums = (float*)walloc(64 * 4);
    float* cnts = (float*)walloc(64 * 4);

    hipMemsetAsync(deg, 0, (size_t)N * 4, stream);
    hipMemsetAsync(acc1, 0, (size_t)N * 16 * 4, stream);
    hipMemsetAsync(acc2, 0, (size_t)N * 4, stream);
    hipMemsetAsync(sums, 0, 64 * 4, stream);
    hipMemsetAsync(cnts, 0, 64 * 4, stream);

    count_deg_kernel<<<(E + TPB - 1) / TPB, TPB, 0, stream>>>(dst, E, deg);
    node_prep_kernel<<<(N + TPB - 1) / TPB, TPB, 0, stream>>>(x, W1, deg, dinv, g1, N);

    long long tot = (long long)E * 16;
    scatter1_kernel<<<(int)((tot + TPB - 1) / TPB), TPB, 0, stream>>>(src, dst, g1, acc1, tot);

    layer1_finish_kernel<<<(N + TPB - 1) / TPB, TPB, 0, stream>>>(acc1, g1, dinv, b1, W2, g2, N);
    scatter2_kernel<<<(E + TPB - 1) / TPB, TPB, 0, stream>>>(src, dst, g2, acc2, E);
    pool_kernel<<<(N + TPB - 1) / TPB, TPB, 0, stream>>>(acc2, g2, dinv, b2, batch, sums, cnts, N);
    finalize_kernel<<<1, 64, 0, stream>>>(sums, cnts, (float*)d_out, G);
}

// Round 2
// 1069.358 us; speedup vs baseline: 1.0899x; 1.0899x over previous
//
#include <hip/hip_runtime.h>
#include <math.h>

// GCN 2-layer + mean-pool + sigmoid, CSR counting-sort formulation.
// out[d] = dinv[d]*(sum_{s->d} g[s] + g[d]) + b,  g = dinv*(h@W)
// Layer 1 aggregation fused with relu + @W2 so acc1 is never materialized.

#define TPB 256
#define SCAN_TPB 256
#define SCAN_ITEMS 8
#define SCAN_CHUNK (SCAN_TPB * SCAN_ITEMS)  // 2048

__global__ void count_deg_kernel(const int* __restrict__ dst, int E, int* __restrict__ deg) {
    int e = blockIdx.x * blockDim.x + threadIdx.x;
    if (e < E) atomicAdd(&deg[dst[e]], 1);
}

// ---- exclusive scan of deg[N] -> rowptr[N+1] (3 kernels) ----
__global__ void scan_reduce_kernel(const int* __restrict__ deg, int N, int* __restrict__ bsum) {
    __shared__ int red[SCAN_TPB];
    int t = threadIdx.x;
    int base = blockIdx.x * SCAN_CHUNK + t * SCAN_ITEMS;
    int s = 0;
#pragma unroll
    for (int k = 0; k < SCAN_ITEMS; ++k) {
        int i = base + k;
        s += (i < N) ? deg[i] : 0;
    }
    red[t] = s;
    __syncthreads();
    for (int d = SCAN_TPB / 2; d > 0; d >>= 1) {
        if (t < d) red[t] += red[t + d];
        __syncthreads();
    }
    if (t == 0) bsum[blockIdx.x] = red[0];
}

// single block: exclusive scan of bsum[nb] in place; write total to rowptr[N]
__global__ void scan_bsum_kernel(int* __restrict__ bsum, int nb, int* __restrict__ rowptr, int N) {
    __shared__ int sd[SCAN_TPB];
    int t = threadIdx.x;
    int v = (t < nb) ? bsum[t] : 0;
    sd[t] = v;
    __syncthreads();
    for (int d = 1; d < SCAN_TPB; d <<= 1) {
        int x = (t >= d) ? sd[t - d] : 0;
        __syncthreads();
        sd[t] += x;
        __syncthreads();
    }
    if (t < nb) bsum[t] = sd[t] - v;           // exclusive
    if (t == SCAN_TPB - 1) rowptr[N] = sd[t];  // total
}

__global__ void scan_write_kernel(const int* __restrict__ deg, int N,
                                  const int* __restrict__ bsum, int* __restrict__ rowptr) {
    __shared__ int sd[SCAN_TPB];
    int t = threadIdx.x;
    int base = blockIdx.x * SCAN_CHUNK + t * SCAN_ITEMS;
    int vals[SCAN_ITEMS];
    int s = 0;
#pragma unroll
    for (int k = 0; k < SCAN_ITEMS; ++k) {
        int i = base + k;
        vals[k] = (i < N) ? deg[i] : 0;
        s += vals[k];
    }
    sd[t] = s;
    __syncthreads();
    for (int d = 1; d < SCAN_TPB; d <<= 1) {
        int x = (t >= d) ? sd[t - d] : 0;
        __syncthreads();
        sd[t] += x;
        __syncthreads();
    }
    int run = bsum[blockIdx.x] + sd[t] - s;  // exclusive offset for this thread
#pragma unroll
    for (int k = 0; k < SCAN_ITEMS; ++k) {
        int i = base + k;
        if (i < N) rowptr[i] = run;
        run += vals[k];
    }
}

// per node: dinv = rsqrt(deg+1);  g1[n][f] = dinv * sum_i x[n][i]*W1[i][f]
__global__ void node_prep_kernel(const float* __restrict__ x, const float* __restrict__ W1,
                                 const int* __restrict__ deg, float* __restrict__ dinv,
                                 float* __restrict__ g1, int N) {
    __shared__ float sW[7 * 16];
    int t = threadIdx.x;
    if (t < 7 * 16) sW[t] = W1[t];
    __syncthreads();
    int n = blockIdx.x * blockDim.x + t;
    if (n >= N) return;
    float di = rsqrtf((float)deg[n] + 1.0f);
    dinv[n] = di;
    float xi[7];
#pragma unroll
    for (int i = 0; i < 7; ++i) xi[i] = x[n * 7 + i];
#pragma unroll
    for (int f = 0; f < 16; ++f) {
        float acc = 0.f;
#pragma unroll
        for (int i = 0; i < 7; ++i) acc = fmaf(xi[i], sW[i * 16 + f], acc);
        g1[(size_t)n * 16 + f] = di * acc;
    }
}

// place src of each edge into dst's CSR segment
__global__ void csr_fill_kernel(const int* __restrict__ src, const int* __restrict__ dst,
                                const int* __restrict__ rowptr, int* __restrict__ cursor,
                                int* __restrict__ csr, int E) {
    int e = blockIdx.x * blockDim.x + threadIdx.x;
    if (e >= E) return;
    int s = src[e];
    int d = dst[e];
    int p = atomicAdd(&cursor[d], 1);
    csr[rowptr[d] + p] = s;
}

// 16 lanes per node: gather-sum g1 over neighbors, finish layer1 (relu, @W2), emit g2
__global__ void gather1_kernel(const int* __restrict__ rowptr, const int* __restrict__ csr,
                               const float* __restrict__ g1, const float* __restrict__ dinv,
                               const float* __restrict__ b1, const float* __restrict__ W2,
                               float* __restrict__ g2, int N) {
    int t = threadIdx.x;
    int f = t & 15;
    int n = blockIdx.x * (TPB / 16) + (t >> 4);
    if (n >= N) return;
    int beg = rowptr[n], end = rowptr[n + 1];
    float acc = g1[(size_t)n * 16 + f];  // self-loop term
    for (int j = beg; j < end; ++j) {
        int s = csr[j];
        acc += g1[(size_t)s * 16 + f];
    }
    float di = dinv[n];
    float h = fmaxf(di * acc + b1[f], 0.f);
    float y = h * W2[f];
    y += __shfl_xor(y, 8, 16);
    y += __shfl_xor(y, 4, 16);
    y += __shfl_xor(y, 2, 16);
    y += __shfl_xor(y, 1, 16);
    if (f == 0) g2[n] = di * y;
}

// per node: gather-sum g2 over neighbors, compute h2, pool into 64 shared bins
__global__ void gather2_pool_kernel(const int* __restrict__ rowptr, const int* __restrict__ csr,
                                    const float* __restrict__ g2, const float* __restrict__ dinv,
                                    const float* __restrict__ b2, const int* __restrict__ batch,
                                    float* __restrict__ sums, float* __restrict__ cnts, int N) {
    __shared__ float ssum[64];
    __shared__ float scnt[64];
    int t = threadIdx.x;
    if (t < 64) { ssum[t] = 0.f; scnt[t] = 0.f; }
    __syncthreads();
    int n = blockIdx.x * blockDim.x + t;
    if (n < N) {
        int beg = rowptr[n], end = rowptr[n + 1];
        float acc = g2[n];  // self-loop term
        for (int j = beg; j < end; ++j) acc += g2[csr[j]];
        float h2 = dinv[n] * acc + b2[0];
        int g = batch[n];
        atomicAdd(&ssum[g], h2);
        atomicAdd(&scnt[g], 1.0f);
    }
    __syncthreads();
    if (t < 64 && scnt[t] != 0.f) {
        atomicAdd(&sums[t], ssum[t]);
        atomicAdd(&cnts[t], scnt[t]);
    }
}

__global__ void finalize_kernel(const float* __restrict__ sums, const float* __restrict__ cnts,
                                float* __restrict__ out, int G) {
    int g = blockIdx.x * blockDim.x + threadIdx.x;
    if (g < G) {
        float m = sums[g] / fmaxf(cnts[g], 1.0f);
        out[g] = 1.0f / (1.0f + expf(-m));
    }
}

extern "C" void kernel_launch(void* const* d_in, const int* in_sizes, int n_in,
                              void* d_out, int out_size, void* d_ws, size_t ws_size,
                              hipStream_t stream) {
    const float* x  = (const float*)d_in[0];
    const float* W1 = (const float*)d_in[1];
    const float* b1 = (const float*)d_in[2];
    const float* W2 = (const float*)d_in[3];
    const float* b2 = (const float*)d_in[4];
    const int* ei   = (const int*)d_in[5];
    const int* batch = (const int*)d_in[6];

    const int N = in_sizes[0] / 7;
    const int E = in_sizes[5] / 2;
    const int G = out_size;
    const int* src = ei;
    const int* dst = ei + E;

    char* ws = (char*)d_ws;
    size_t off = 0;
    auto walloc = [&](size_t bytes) -> void* {
        void* p = ws + off;
        off += (bytes + 255) & ~(size_t)255;
        return p;
    };
    int*   deg    = (int*)  walloc((size_t)N * 4);        // reused as cursor for csr_fill
    int*   rowptr = (int*)  walloc((size_t)(N + 1) * 4);
    float* dinv   = (float*)walloc((size_t)N * 4);
    float* g1     = (float*)walloc((size_t)N * 16 * 4);
    int*   csr    = (int*)  walloc((size_t)E * 4);
    float* g2     = (float*)walloc((size_t)N * 4);
    int*   bsum   = (int*)  walloc(1024 * 4);
    float* sums   = (float*)walloc(64 * 4);
    float* cnts   = (float*)walloc(64 * 4);

    const int NBLK_SCAN = (N + SCAN_CHUNK - 1) / SCAN_CHUNK;  // 245 (< 256)

    hipMemsetAsync(deg, 0, (size_t)N * 4, stream);
    hipMemsetAsync(sums, 0, 64 * 4, stream);
    hipMemsetAsync(cnts, 0, 64 * 4, stream);

    count_deg_kernel<<<(E + TPB - 1) / TPB, TPB, 0, stream>>>(dst, E, deg);

    scan_reduce_kernel<<<NBLK_SCAN, SCAN_TPB, 0, stream>>>(deg, N, bsum);
    scan_bsum_kernel<<<1, SCAN_TPB, 0, stream>>>(bsum, NBLK_SCAN, rowptr, N);
    scan_write_kernel<<<NBLK_SCAN, SCAN_TPB, 0, stream>>>(deg, N, bsum, rowptr);

    node_prep_kernel<<<(N + TPB - 1) / TPB, TPB, 0, stream>>>(x, W1, deg, dinv, g1, N);

    hipMemsetAsync(deg, 0, (size_t)N * 4, stream);  // deg becomes cursor
    csr_fill_kernel<<<(E + TPB - 1) / TPB, TPB, 0, stream>>>(src, dst, rowptr, deg, csr, E);

    gather1_kernel<<<(N * 16 + TPB - 1) / TPB, TPB, 0, stream>>>(rowptr, csr, g1, dinv, b1, W2, g2, N);
    gather2_pool_kernel<<<(N + TPB - 1) / TPB, TPB, 0, stream>>>(rowptr, csr, g2, dinv, b2, batch, sums, cnts, N);
    finalize_kernel<<<1, 64, 0, stream>>>(sums, cnts, (float*)d_out, G);
}

// Round 3
// 907.413 us; speedup vs baseline: 1.2844x; 1.1785x over previous
//
#include <hip/hip_runtime.h>
#include <math.h>

// GCN 2-layer + mean-pool + sigmoid, bucketed-scatter formulation.
// out[d] = dinv[d]*(sum_{s->d} g[s] + g[d]) + b,  g = dinv*(h@W).
// Nodes partitioned into buckets of 512; edges counting-sorted by bucket with
// packed payload (src<<9)|dstLocal; per-bucket accumulation happens in LDS.

#define TPB 256
#define NBNODES 512   // nodes per bucket = 2^LOG_NB
#define LOG_NB 9
#define MAXBUCK 1024  // >= nbuck (977)
#define CHUNK 16384   // edges per scatter block
#define ACCPAD 17     // LDS stride (floats) per node to spread banks

// ---- 1) count edges per bucket ----
__global__ void bucket_count_kernel(const int* __restrict__ dst, int E, int nbuck,
                                    int* __restrict__ bucket_cnt) {
    __shared__ int hist[MAXBUCK];
    for (int b = threadIdx.x; b < nbuck; b += blockDim.x) hist[b] = 0;
    __syncthreads();
    for (int e = blockIdx.x * blockDim.x + threadIdx.x; e < E; e += gridDim.x * blockDim.x)
        atomicAdd(&hist[dst[e] >> LOG_NB], 1);
    __syncthreads();
    for (int b = threadIdx.x; b < nbuck; b += blockDim.x)
        if (hist[b]) atomicAdd(&bucket_cnt[b], hist[b]);
}

// ---- 2) exclusive scan of bucket_cnt -> ptr[nbuck+1] (single block) ----
__global__ void bucket_scan_kernel(const int* __restrict__ cnt, int nbuck, int* __restrict__ ptr) {
    __shared__ int sd[MAXBUCK];
    int t = threadIdx.x;
    sd[t] = (t < nbuck) ? cnt[t] : 0;
    __syncthreads();
    for (int d = 1; d < MAXBUCK; d <<= 1) {
        int x = (t >= d) ? sd[t - d] : 0;
        __syncthreads();
        sd[t] += x;
        __syncthreads();
    }
    if (t < nbuck) ptr[t + 1] = sd[t];
    if (t == 0) ptr[0] = 0;
}

// ---- 3) scatter edges into bucket segments, payload packed (src<<9)|dstLocal ----
__global__ void bucket_scatter_kernel(const int* __restrict__ src, const int* __restrict__ dst,
                                      int E, int nbuck, int* __restrict__ gcursor,
                                      int* __restrict__ bpack) {
    __shared__ int hist[MAXBUCK];
    __shared__ int cur[MAXBUCK];
    __shared__ int basea[MAXBUCK];
    int t = threadIdx.x;
    for (int b = t; b < nbuck; b += blockDim.x) { hist[b] = 0; cur[b] = 0; }
    __syncthreads();
    int c0 = blockIdx.x * CHUNK;
    int cend = min(CHUNK, E - c0);
    for (int k = t; k < cend; k += blockDim.x)
        atomicAdd(&hist[dst[c0 + k] >> LOG_NB], 1);
    __syncthreads();
    for (int b = t; b < nbuck; b += blockDim.x)
        if (hist[b] > 0) basea[b] = atomicAdd(&gcursor[b], hist[b]);
    __syncthreads();
    for (int k = t; k < cend; k += blockDim.x) {
        int d = dst[c0 + k];
        int s = src[c0 + k];
        int b = d >> LOG_NB;
        int p = atomicAdd(&cur[b], 1);
        bpack[basea[b] + p] = (s << LOG_NB) | (d & (NBNODES - 1));
    }
}

// ---- 4) per-bucket in-degree -> dinv ----
__global__ __launch_bounds__(512) void dinv_kernel(const int* __restrict__ ptr,
                                                   const int* __restrict__ bpack,
                                                   float* __restrict__ dinv, int N) {
    __shared__ int cnt[NBNODES];
    int t = threadIdx.x;
    for (int i = t; i < NBNODES; i += 512) cnt[i] = 0;
    __syncthreads();
    int bu = blockIdx.x;
    int beg = ptr[bu], end = ptr[bu + 1];
    for (int e = beg + t; e < end; e += 512)
        atomicAdd(&cnt[bpack[e] & (NBNODES - 1)], 1);
    __syncthreads();
    int n0 = bu << LOG_NB;
    for (int i = t; i < NBNODES; i += 512) {
        int n = n0 + i;
        if (n < N) dinv[n] = rsqrtf((float)cnt[i] + 1.0f);  // +1 self-loop
    }
}

// ---- 5) g1[n][f] = dinv[n] * (x @ W1)[n][f] ----
__global__ void node_prep_kernel(const float* __restrict__ x, const float* __restrict__ W1,
                                 const float* __restrict__ dinv, float* __restrict__ g1, int N) {
    __shared__ float sW[7 * 16];
    int t = threadIdx.x;
    if (t < 7 * 16) sW[t] = W1[t];
    __syncthreads();
    int n = blockIdx.x * blockDim.x + t;
    if (n >= N) return;
    float di = dinv[n];
    float xi[7];
#pragma unroll
    for (int i = 0; i < 7; ++i) xi[i] = x[n * 7 + i];
#pragma unroll
    for (int f = 0; f < 16; ++f) {
        float acc = 0.f;
#pragma unroll
        for (int i = 0; i < 7; ++i) acc = fmaf(xi[i], sW[i * 16 + f], acc);
        g1[(size_t)n * 16 + f] = di * acc;
    }
}

// ---- 6) per-bucket layer-1 aggregation in LDS + fused relu/@W2 -> g2 ----
__global__ __launch_bounds__(512) void acc1_kernel(const int* __restrict__ ptr,
                                                   const int* __restrict__ bpack,
                                                   const float* __restrict__ g1,
                                                   const float* __restrict__ dinv,
                                                   const float* __restrict__ b1,
                                                   const float* __restrict__ W2,
                                                   float* __restrict__ g2, int N) {
    __shared__ float acc[NBNODES * ACCPAD];
    __shared__ float sb1[16], sw2[16];
    int t = threadIdx.x;
    if (t < 16) { sb1[t] = b1[t]; sw2[t] = W2[t]; }
    for (int i = t; i < NBNODES * ACCPAD; i += 512) acc[i] = 0.f;
    __syncthreads();
    int bu = blockIdx.x;
    int beg = ptr[bu], end = ptr[bu + 1];
    int f = t & 15, sub = t >> 4;  // 32 edges in flight
    for (int e = beg + sub; e < end; e += 32) {
        int v = bpack[e];
        int s = v >> LOG_NB;
        int d = v & (NBNODES - 1);
        atomicAdd(&acc[d * ACCPAD + f], g1[(size_t)s * 16 + f]);
    }
    __syncthreads();
    int n0 = bu << LOG_NB;
    for (int i = t; i < NBNODES; i += 512) {
        int n = n0 + i;
        if (n >= N) continue;
        float di = dinv[n];
        float y = 0.f;
#pragma unroll
        for (int ff = 0; ff < 16; ++ff) {
            float tot = acc[i * ACCPAD + ff] + g1[(size_t)n * 16 + ff];  // + self-loop
            float h = fmaxf(di * tot + sb1[ff], 0.f);
            y = fmaf(h, sw2[ff], y);
        }
        g2[n] = di * y;
    }
}

// ---- 7) per-bucket layer-2 aggregation + fused mean-pool binning ----
__global__ __launch_bounds__(512) void acc2_pool_kernel(const int* __restrict__ ptr,
                                                        const int* __restrict__ bpack,
                                                        const float* __restrict__ g2,
                                                        const float* __restrict__ dinv,
                                                        const float* __restrict__ b2,
                                                        const int* __restrict__ batch,
                                                        float* __restrict__ sums,
                                                        float* __restrict__ cnts, int N) {
    __shared__ float acc[NBNODES];
    __shared__ float ssum[64], scnt[64];
    int t = threadIdx.x;
    for (int i = t; i < NBNODES; i += 512) acc[i] = 0.f;
    if (t < 64) { ssum[t] = 0.f; scnt[t] = 0.f; }
    __syncthreads();
    int bu = blockIdx.x;
    int beg = ptr[bu], end = ptr[bu + 1];
    for (int e = beg + t; e < end; e += 512) {
        int v = bpack[e];
        atomicAdd(&acc[v & (NBNODES - 1)], g2[v >> LOG_NB]);
    }
    __syncthreads();
    int n0 = bu << LOG_NB;
    float bb = b2[0];
    for (int i = t; i < NBNODES; i += 512) {
        int n = n0 + i;
        if (n >= N) continue;
        float h2 = dinv[n] * (acc[i] + g2[n]) + bb;
        int g = batch[n];
        atomicAdd(&ssum[g], h2);
        atomicAdd(&scnt[g], 1.0f);
    }
    __syncthreads();
    if (t < 64 && scnt[t] != 0.f) {
        atomicAdd(&sums[t], ssum[t]);
        atomicAdd(&cnts[t], scnt[t]);
    }
}

__global__ void finalize_kernel(const float* __restrict__ sums, const float* __restrict__ cnts,
                                float* __restrict__ out, int G) {
    int g = blockIdx.x * blockDim.x + threadIdx.x;
    if (g < G) {
        float m = sums[g] / fmaxf(cnts[g], 1.0f);
        out[g] = 1.0f / (1.0f + expf(-m));
    }
}

extern "C" void kernel_launch(void* const* d_in, const int* in_sizes, int n_in,
                              void* d_out, int out_size, void* d_ws, size_t ws_size,
                              hipStream_t stream) {
    const float* x  = (const float*)d_in[0];
    const float* W1 = (const float*)d_in[1];
    const float* b1 = (const float*)d_in[2];
    const float* W2 = (const float*)d_in[3];
    const float* b2 = (const float*)d_in[4];
    const int* ei   = (const int*)d_in[5];
    const int* batch = (const int*)d_in[6];

    const int N = in_sizes[0] / 7;   // 500000 (< 2^19, required for packing)
    const int E = in_sizes[5] / 2;   // 8000000
    const int G = out_size;          // 64
    const int* src = ei;
    const int* dst = ei + E;
    const int nbuck = (N + NBNODES - 1) >> LOG_NB;  // 977
    const int nchunk = (E + CHUNK - 1) / CHUNK;     // 489

    char* ws = (char*)d_ws;
    size_t off = 0;
    auto walloc = [&](size_t bytes) -> void* {
        void* p = ws + off;
        off += (bytes + 255) & ~(size_t)255;
        return p;
    };
    int*   bucket_cnt = (int*)  walloc((size_t)MAXBUCK * 4);
    int*   ptr        = (int*)  walloc((size_t)(MAXBUCK + 1) * 4);
    int*   gcursor    = (int*)  walloc((size_t)MAXBUCK * 4);
    float* dinv       = (float*)walloc((size_t)N * 4);
    float* g1         = (float*)walloc((size_t)N * 16 * 4);
    int*   bpack      = (int*)  walloc((size_t)E * 4);
    float* g2         = (float*)walloc((size_t)N * 4);
    float* sums       = (float*)walloc(64 * 4);
    float* cnts       = (float*)walloc(64 * 4);

    hipMemsetAsync(bucket_cnt, 0, (size_t)MAXBUCK * 4, stream);
    hipMemsetAsync(sums, 0, 64 * 4, stream);
    hipMemsetAsync(cnts, 0, 64 * 4, stream);

    bucket_count_kernel<<<512, TPB, 0, stream>>>(dst, E, nbuck, bucket_cnt);
    bucket_scan_kernel<<<1, MAXBUCK, 0, stream>>>(bucket_cnt, nbuck, ptr);
    hipMemcpyAsync(gcursor, ptr, (size_t)nbuck * 4, hipMemcpyDeviceToDevice, stream);
    bucket_scatter_kernel<<<nchunk, TPB, 0, stream>>>(src, dst, E, nbuck, gcursor, bpack);

    dinv_kernel<<<nbuck, 512, 0, stream>>>(ptr, bpack, dinv, N);
    node_prep_kernel<<<(N + TPB - 1) / TPB, TPB, 0, stream>>>(x, W1, dinv, g1, N);
    acc1_kernel<<<nbuck, 512, 0, stream>>>(ptr, bpack, g1, dinv, b1, W2, g2, N);
    acc2_pool_kernel<<<nbuck, 512, 0, stream>>>(ptr, bpack, g2, dinv, b2, batch, sums, cnts, N);
    finalize_kernel<<<1, 64, 0, stream>>>(sums, cnts, (float*)d_out, G);
}

// Round 4
// 562.484 us; speedup vs baseline: 2.0720x; 1.6132x over previous
//
#include <hip/hip_runtime.h>
#include <math.h>

// GCN 2-layer + mean-pool + sigmoid, bucketed-scatter formulation.
// out[d] = dinv[d]*(sum_{s->d} g[s] + g[d]) + b,  g = dinv*(h@W).
// Aggregation done in 7-dim input space (linearity): payload xd = dinv*[x,1] (32B).
// Nodes in buckets of 512; edges counting-sorted by bucket, payload (src<<9)|dstLocal;
// per-bucket accumulation in LDS with 4x-unrolled independent gathers for MLP.

#define TPB 256
#define NBNODES 512   // nodes per bucket = 2^LOG_NB
#define LOG_NB 9
#define MAXBUCK 1024  // >= nbuck (977)
#define CHUNK 16384   // edges per scatter block
#define APAD 9        // LDS stride (floats) per node in acc1 tile

// ---- 1) count edges per bucket ----
__global__ void bucket_count_kernel(const int* __restrict__ dst, int E, int nbuck,
                                    int* __restrict__ bucket_cnt) {
    __shared__ int hist[MAXBUCK];
    for (int b = threadIdx.x; b < nbuck; b += blockDim.x) hist[b] = 0;
    __syncthreads();
    for (int e = blockIdx.x * blockDim.x + threadIdx.x; e < E; e += gridDim.x * blockDim.x)
        atomicAdd(&hist[dst[e] >> LOG_NB], 1);
    __syncthreads();
    for (int b = threadIdx.x; b < nbuck; b += blockDim.x)
        if (hist[b]) atomicAdd(&bucket_cnt[b], hist[b]);
}

// ---- 2) exclusive scan of bucket_cnt -> ptr[nbuck+1] (single block) ----
__global__ void bucket_scan_kernel(const int* __restrict__ cnt, int nbuck, int* __restrict__ ptr) {
    __shared__ int sd[MAXBUCK];
    int t = threadIdx.x;
    sd[t] = (t < nbuck) ? cnt[t] : 0;
    __syncthreads();
    for (int d = 1; d < MAXBUCK; d <<= 1) {
        int x = (t >= d) ? sd[t - d] : 0;
        __syncthreads();
        sd[t] += x;
        __syncthreads();
    }
    if (t < nbuck) ptr[t + 1] = sd[t];
    if (t == 0) ptr[0] = 0;
}

// ---- 3) scatter edges into bucket segments, payload packed (src<<9)|dstLocal ----
__global__ void bucket_scatter_kernel(const int* __restrict__ src, const int* __restrict__ dst,
                                      int E, int nbuck, int* __restrict__ gcursor,
                                      int* __restrict__ bpack) {
    __shared__ int hist[MAXBUCK];
    __shared__ int cur[MAXBUCK];
    __shared__ int basea[MAXBUCK];
    int t = threadIdx.x;
    for (int b = t; b < nbuck; b += blockDim.x) { hist[b] = 0; cur[b] = 0; }
    __syncthreads();
    int c0 = blockIdx.x * CHUNK;
    int cend = min(CHUNK, E - c0);
    for (int k = t; k < cend; k += blockDim.x)
        atomicAdd(&hist[dst[c0 + k] >> LOG_NB], 1);
    __syncthreads();
    for (int b = t; b < nbuck; b += blockDim.x)
        if (hist[b] > 0) basea[b] = atomicAdd(&gcursor[b], hist[b]);
    __syncthreads();
    for (int k = t; k < cend; k += blockDim.x) {
        int d = dst[c0 + k];
        int s = src[c0 + k];
        int b = d >> LOG_NB;
        int p = atomicAdd(&cur[b], 1);
        bpack[basea[b] + p] = (s << LOG_NB) | (d & (NBNODES - 1));
    }
}

// ---- 4) per-bucket in-degree -> dinv ----
__global__ __launch_bounds__(512) void dinv_kernel(const int* __restrict__ ptr,
                                                   const int* __restrict__ bpack,
                                                   float* __restrict__ dinv, int N) {
    __shared__ int cnt[NBNODES];
    int t = threadIdx.x;
    for (int i = t; i < NBNODES; i += 512) cnt[i] = 0;
    __syncthreads();
    int bu = blockIdx.x;
    int beg = ptr[bu], end = ptr[bu + 1];
    for (int e = beg + t; e < end; e += 512)
        atomicAdd(&cnt[bpack[e] & (NBNODES - 1)], 1);
    __syncthreads();
    int n0 = bu << LOG_NB;
    for (int i = t; i < NBNODES; i += 512) {
        int n = n0 + i;
        if (n < N) dinv[n] = rsqrtf((float)cnt[i] + 1.0f);  // +1 self-loop
    }
}

// ---- 5) xd[n][i] = dinv[n]*x[n][i] (i<7), xd[n][7] = dinv[n] ----
__global__ void xd_prep_kernel(const float* __restrict__ x, const float* __restrict__ dinv,
                               float* __restrict__ xd, int N) {
    int n = blockIdx.x * blockDim.x + threadIdx.x;
    if (n >= N) return;
    float di = dinv[n];
#pragma unroll
    for (int i = 0; i < 7; ++i) xd[(size_t)n * 8 + i] = di * x[(size_t)n * 7 + i];
    xd[(size_t)n * 8 + 7] = di;
}

// ---- 6) per-bucket 7-dim aggregation in LDS, then fused @W1+relu+@W2 -> g2 ----
__global__ __launch_bounds__(512) void acc1_kernel(const int* __restrict__ ptr,
                                                   const int* __restrict__ bpack,
                                                   const float* __restrict__ xd,
                                                   const float* __restrict__ W1,
                                                   const float* __restrict__ b1,
                                                   const float* __restrict__ W2,
                                                   float* __restrict__ g2, int N) {
    __shared__ float acc[NBNODES * APAD];
    __shared__ float sW1[7 * 16];
    __shared__ float sb1[16], sw2[16];
    int t = threadIdx.x;
    if (t < 112) sW1[t] = W1[t];
    else if (t < 128) sb1[t - 112] = b1[t - 112];
    else if (t < 144) sw2[t - 128] = W2[t - 128];
    for (int i = t; i < NBNODES * APAD; i += 512) acc[i] = 0.f;
    __syncthreads();
    int bu = blockIdx.x;
    int beg = ptr[bu], end = ptr[bu + 1];
    int f = t & 7, sub = t >> 3;  // 64 edge-groups of 8 lanes
    int e = beg + sub;
    for (; e + 192 < end; e += 256) {  // 4x unroll: independent loads for MLP
        int v0 = bpack[e];
        int v1 = bpack[e + 64];
        int v2 = bpack[e + 128];
        int v3 = bpack[e + 192];
        float a0 = xd[(size_t)(v0 >> LOG_NB) * 8 + f];
        float a1 = xd[(size_t)(v1 >> LOG_NB) * 8 + f];
        float a2 = xd[(size_t)(v2 >> LOG_NB) * 8 + f];
        float a3 = xd[(size_t)(v3 >> LOG_NB) * 8 + f];
        atomicAdd(&acc[(v0 & (NBNODES - 1)) * APAD + f], a0);
        atomicAdd(&acc[(v1 & (NBNODES - 1)) * APAD + f], a1);
        atomicAdd(&acc[(v2 & (NBNODES - 1)) * APAD + f], a2);
        atomicAdd(&acc[(v3 & (NBNODES - 1)) * APAD + f], a3);
    }
    for (; e < end; e += 64) {
        int v = bpack[e];
        atomicAdd(&acc[(v & (NBNODES - 1)) * APAD + f], xd[(size_t)(v >> LOG_NB) * 8 + f]);
    }
    __syncthreads();
    int n0 = bu << LOG_NB;
    for (int i = t; i < NBNODES; i += 512) {
        int n = n0 + i;
        if (n >= N) continue;
        float di = xd[(size_t)n * 8 + 7];  // dinv packed in slot 7
        float ax[7];
#pragma unroll
        for (int k = 0; k < 7; ++k) ax[k] = acc[i * APAD + k] + xd[(size_t)n * 8 + k];  // + self
        float y = 0.f;
#pragma unroll
        for (int ff = 0; ff < 16; ++ff) {
            float h = 0.f;
#pragma unroll
            for (int k = 0; k < 7; ++k) h = fmaf(ax[k], sW1[k * 16 + ff], h);
            h = fmaxf(di * h + sb1[ff], 0.f);
            y = fmaf(h, sw2[ff], y);
        }
        g2[n] = di * y;
    }
}

// ---- 7) per-bucket layer-2 aggregation + fused mean-pool binning ----
__global__ __launch_bounds__(512) void acc2_pool_kernel(const int* __restrict__ ptr,
                                                        const int* __restrict__ bpack,
                                                        const float* __restrict__ g2,
                                                        const float* __restrict__ xd,
                                                        const float* __restrict__ b2,
                                                        const int* __restrict__ batch,
                                                        float* __restrict__ sums,
                                                        float* __restrict__ cnts, int N) {
    __shared__ float acc[NBNODES];
    __shared__ float ssum[64], scnt[64];
    int t = threadIdx.x;
    for (int i = t; i < NBNODES; i += 512) acc[i] = 0.f;
    if (t < 64) { ssum[t] = 0.f; scnt[t] = 0.f; }
    __syncthreads();
    int bu = blockIdx.x;
    int beg = ptr[bu], end = ptr[bu + 1];
    int e = beg + t;
    for (; e + 1536 < end; e += 2048) {  // 4x unroll
        int v0 = bpack[e];
        int v1 = bpack[e + 512];
        int v2 = bpack[e + 1024];
        int v3 = bpack[e + 1536];
        float a0 = g2[v0 >> LOG_NB];
        float a1 = g2[v1 >> LOG_NB];
        float a2 = g2[v2 >> LOG_NB];
        float a3 = g2[v3 >> LOG_NB];
        atomicAdd(&acc[v0 & (NBNODES - 1)], a0);
        atomicAdd(&acc[v1 & (NBNODES - 1)], a1);
        atomicAdd(&acc[v2 & (NBNODES - 1)], a2);
        atomicAdd(&acc[v3 & (NBNODES - 1)], a3);
    }
    for (; e < end; e += 512) {
        int v = bpack[e];
        atomicAdd(&acc[v & (NBNODES - 1)], g2[v >> LOG_NB]);
    }
    __syncthreads();
    int n0 = bu << LOG_NB;
    float bb = b2[0];
    for (int i = t; i < NBNODES; i += 512) {
        int n = n0 + i;
        if (n >= N) continue;
        float di = xd[(size_t)n * 8 + 7];
        float h2 = di * (acc[i] + g2[n]) + bb;
        int g = batch[n];
        atomicAdd(&ssum[g], h2);
        atomicAdd(&scnt[g], 1.0f);
    }
    __syncthreads();
    if (t < 64 && scnt[t] != 0.f) {
        atomicAdd(&sums[t], ssum[t]);
        atomicAdd(&cnts[t], scnt[t]);
    }
}

__global__ void finalize_kernel(const float* __restrict__ sums, const float* __restrict__ cnts,
                                float* __restrict__ out, int G) {
    int g = blockIdx.x * blockDim.x + threadIdx.x;
    if (g < G) {
        float m = sums[g] / fmaxf(cnts[g], 1.0f);
        out[g] = 1.0f / (1.0f + expf(-m));
    }
}

extern "C" void kernel_launch(void* const* d_in, const int* in_sizes, int n_in,
                              void* d_out, int out_size, void* d_ws, size_t ws_size,
                              hipStream_t stream) {
    const float* x  = (const float*)d_in[0];
    const float* W1 = (const float*)d_in[1];
    const float* b1 = (const float*)d_in[2];
    const float* W2 = (const float*)d_in[3];
    const float* b2 = (const float*)d_in[4];
    const int* ei   = (const int*)d_in[5];
    const int* batch = (const int*)d_in[6];

    const int N = in_sizes[0] / 7;   // 500000 (< 2^19, required for packing)
    const int E = in_sizes[5] / 2;   // 8000000
    const int G = out_size;          // 64
    const int* src = ei;
    const int* dst = ei + E;
    const int nbuck = (N + NBNODES - 1) >> LOG_NB;  // 977
    const int nchunk = (E + CHUNK - 1) / CHUNK;     // 489

    char* ws = (char*)d_ws;
    size_t off = 0;
    auto walloc = [&](size_t bytes) -> void* {
        void* p = ws + off;
        off += (bytes + 255) & ~(size_t)255;
        return p;
    };
    int*   bucket_cnt = (int*)  walloc((size_t)MAXBUCK * 4);
    int*   ptr        = (int*)  walloc((size_t)(MAXBUCK + 1) * 4);
    int*   gcursor    = (int*)  walloc((size_t)MAXBUCK * 4);
    float* dinv       = (float*)walloc((size_t)N * 4);
    float* xd         = (float*)walloc((size_t)N * 8 * 4);
    int*   bpack      = (int*)  walloc((size_t)E * 4);
    float* g2         = (float*)walloc((size_t)N * 4);
    float* sums       = (float*)walloc(64 * 4);
    float* cnts       = (float*)walloc(64 * 4);

    hipMemsetAsync(bucket_cnt, 0, (size_t)MAXBUCK * 4, stream);
    hipMemsetAsync(sums, 0, 64 * 4, stream);
    hipMemsetAsync(cnts, 0, 64 * 4, stream);

    bucket_count_kernel<<<512, TPB, 0, stream>>>(dst, E, nbuck, bucket_cnt);
    bucket_scan_kernel<<<1, MAXBUCK, 0, stream>>>(bucket_cnt, nbuck, ptr);
    hipMemcpyAsync(gcursor, ptr, (size_t)nbuck * 4, hipMemcpyDeviceToDevice, stream);
    bucket_scatter_kernel<<<nchunk, TPB, 0, stream>>>(src, dst, E, nbuck, gcursor, bpack);

    dinv_kernel<<<nbuck, 512, 0, stream>>>(ptr, bpack, dinv, N);
    xd_prep_kernel<<<(N + TPB - 1) / TPB, TPB, 0, stream>>>(x, dinv, xd, N);
    acc1_kernel<<<nbuck, 512, 0, stream>>>(ptr, bpack, xd, W1, b1, W2, g2, N);
    acc2_pool_kernel<<<nbuck, 512, 0, stream>>>(ptr, bpack, g2, xd, b2, batch, sums, cnts, N);
    finalize_kernel<<<1, 64, 0, stream>>>(sums, cnts, (float*)d_out, G);
}

// Round 5
// 536.605 us; speedup vs baseline: 2.1719x; 1.0482x over previous
//
#include <hip/hip_runtime.h>
#include <math.h>

// GCN 2-layer + mean-pool + sigmoid, bucketed-scatter formulation.
// out[d] = dinv[d]*(sum_{s->d} g[s] + g[d]) + b,  g = dinv*(h@W).
// Aggregation in 7-dim input space (linearity): payload xd = dinv*[x,1] (32B).
// Nodes in buckets of 256; edges counting-sorted by bucket, payload (src<<8)|dstLocal;
// per-bucket accumulation in LDS; ONE LANE PER EDGE -> 64 lines in flight per wave.

#define TPB 256
#define NBNODES 256   // nodes per bucket = 2^LOG_NB
#define LOG_NB 8
#define MAXBUCK 2048  // >= nbuck (1954)
#define CHUNK 32768   // edges per scatter block
#define APAD 9        // LDS stride (floats) per node in acc1 tile (coprime w/ 32 banks)

// ---- 1) count edges per bucket ----
__global__ void bucket_count_kernel(const int* __restrict__ dst, int E, int nbuck,
                                    int* __restrict__ bucket_cnt) {
    __shared__ int hist[MAXBUCK];
    for (int b = threadIdx.x; b < nbuck; b += blockDim.x) hist[b] = 0;
    __syncthreads();
    for (int e = blockIdx.x * blockDim.x + threadIdx.x; e < E; e += gridDim.x * blockDim.x)
        atomicAdd(&hist[dst[e] >> LOG_NB], 1);
    __syncthreads();
    for (int b = threadIdx.x; b < nbuck; b += blockDim.x)
        if (hist[b]) atomicAdd(&bucket_cnt[b], hist[b]);
}

// ---- 2) exclusive scan of bucket_cnt -> ptr[nbuck+1]; 1024 threads scan 2048 ----
__global__ __launch_bounds__(1024) void bucket_scan_kernel(const int* __restrict__ cnt,
                                                           int nbuck, int* __restrict__ ptr) {
    __shared__ int buf[2][1024];
    int t = threadIdx.x;
    int a = (2 * t < nbuck) ? cnt[2 * t] : 0;
    int b = (2 * t + 1 < nbuck) ? cnt[2 * t + 1] : 0;
    int s = a + b;
    buf[0][t] = s;
    __syncthreads();
    int pp = 0;
    for (int d = 1; d < 1024; d <<= 1) {
        int v = buf[pp][t] + ((t >= d) ? buf[pp][t - d] : 0);
        buf[pp ^ 1][t] = v;
        pp ^= 1;
        __syncthreads();
    }
    int excl = buf[pp][t] - s;  // exclusive sum of pairs before this thread
    if (t == 0) ptr[0] = 0;
    if (2 * t < nbuck) ptr[2 * t + 1] = excl + a;
    if (2 * t + 1 < nbuck) ptr[2 * t + 2] = excl + s;
}

// ---- 3) scatter edges into bucket segments, payload packed (src<<8)|dstLocal ----
__global__ void bucket_scatter_kernel(const int* __restrict__ src, const int* __restrict__ dst,
                                      int E, int nbuck, int* __restrict__ gcursor,
                                      int* __restrict__ bpack) {
    __shared__ int hist[MAXBUCK];
    __shared__ int cur[MAXBUCK];
    __shared__ int basea[MAXBUCK];
    int t = threadIdx.x;
    for (int b = t; b < nbuck; b += blockDim.x) { hist[b] = 0; cur[b] = 0; }
    __syncthreads();
    int c0 = blockIdx.x * CHUNK;
    int cend = min(CHUNK, E - c0);
    for (int k = t; k < cend; k += blockDim.x)
        atomicAdd(&hist[dst[c0 + k] >> LOG_NB], 1);
    __syncthreads();
    for (int b = t; b < nbuck; b += blockDim.x)
        if (hist[b] > 0) basea[b] = atomicAdd(&gcursor[b], hist[b]);
    __syncthreads();
    for (int k = t; k < cend; k += blockDim.x) {
        int d = dst[c0 + k];
        int s = src[c0 + k];
        int b = d >> LOG_NB;
        int p = atomicAdd(&cur[b], 1);
        bpack[basea[b] + p] = (s << LOG_NB) | (d & (NBNODES - 1));
    }
}

// ---- 4) per-bucket in-degree -> dinv ----
__global__ __launch_bounds__(TPB) void dinv_kernel(const int* __restrict__ ptr,
                                                   const int* __restrict__ bpack,
                                                   float* __restrict__ dinv, int N) {
    __shared__ int cnt[NBNODES];
    int t = threadIdx.x;
    cnt[t] = 0;
    __syncthreads();
    int bu = blockIdx.x;
    int beg = ptr[bu], end = ptr[bu + 1];
    for (int e = beg + t; e < end; e += TPB)
        atomicAdd(&cnt[bpack[e] & (NBNODES - 1)], 1);
    __syncthreads();
    int n = (bu << LOG_NB) + t;
    if (n < N) dinv[n] = rsqrtf((float)cnt[t] + 1.0f);  // +1 self-loop
}

// ---- 5) xd[n][i] = dinv[n]*x[n][i] (i<7), xd[n][7] = dinv[n] ----
__global__ void xd_prep_kernel(const float* __restrict__ x, const float* __restrict__ dinv,
                               float* __restrict__ xd, int N) {
    int n = blockIdx.x * blockDim.x + threadIdx.x;
    if (n >= N) return;
    float di = dinv[n];
#pragma unroll
    for (int i = 0; i < 7; ++i) xd[(size_t)n * 8 + i] = di * x[(size_t)n * 7 + i];
    xd[(size_t)n * 8 + 7] = di;
}

// ---- 6) per-bucket 7-dim aggregation in LDS, then fused @W1+relu+@W2 -> g2 ----
// one lane per edge: two independent float4 gathers, 8 LDS atomics.
__global__ __launch_bounds__(TPB) void acc1_kernel(const int* __restrict__ ptr,
                                                   const int* __restrict__ bpack,
                                                   const float* __restrict__ xd,
                                                   const float* __restrict__ W1,
                                                   const float* __restrict__ b1,
                                                   const float* __restrict__ W2,
                                                   float* __restrict__ g2, int N) {
    __shared__ float acc[NBNODES * APAD];
    __shared__ float sW1[7 * 16];
    __shared__ float sb1[16], sw2[16];
    int t = threadIdx.x;
    if (t < 112) sW1[t] = W1[t];
    else if (t < 128) sb1[t - 112] = b1[t - 112];
    else if (t < 144) sw2[t - 128] = W2[t - 128];
    for (int i = t; i < NBNODES * APAD; i += TPB) acc[i] = 0.f;
    __syncthreads();
    int bu = blockIdx.x;
    int beg = ptr[bu], end = ptr[bu + 1];
    int e = beg + t;
    for (; e + TPB < end; e += 2 * TPB) {  // 2x unroll, 4 independent lines/lane
        int v0 = bpack[e];
        int v1 = bpack[e + TPB];
        const float4* p0 = (const float4*)(xd + (size_t)(v0 >> LOG_NB) * 8);
        const float4* p1 = (const float4*)(xd + (size_t)(v1 >> LOG_NB) * 8);
        float4 a0 = p0[0], b0 = p0[1];
        float4 a1 = p1[0], b1v = p1[1];
        int d0 = (v0 & (NBNODES - 1)) * APAD;
        int d1 = (v1 & (NBNODES - 1)) * APAD;
        atomicAdd(&acc[d0 + 0], a0.x); atomicAdd(&acc[d0 + 1], a0.y);
        atomicAdd(&acc[d0 + 2], a0.z); atomicAdd(&acc[d0 + 3], a0.w);
        atomicAdd(&acc[d0 + 4], b0.x); atomicAdd(&acc[d0 + 5], b0.y);
        atomicAdd(&acc[d0 + 6], b0.z);
        atomicAdd(&acc[d1 + 0], a1.x); atomicAdd(&acc[d1 + 1], a1.y);
        atomicAdd(&acc[d1 + 2], a1.z); atomicAdd(&acc[d1 + 3], a1.w);
        atomicAdd(&acc[d1 + 4], b1v.x); atomicAdd(&acc[d1 + 5], b1v.y);
        atomicAdd(&acc[d1 + 6], b1v.z);
    }
    for (; e < end; e += TPB) {
        int v = bpack[e];
        const float4* p = (const float4*)(xd + (size_t)(v >> LOG_NB) * 8);
        float4 a = p[0], b = p[1];
        int d = (v & (NBNODES - 1)) * APAD;
        atomicAdd(&acc[d + 0], a.x); atomicAdd(&acc[d + 1], a.y);
        atomicAdd(&acc[d + 2], a.z); atomicAdd(&acc[d + 3], a.w);
        atomicAdd(&acc[d + 4], b.x); atomicAdd(&acc[d + 5], b.y);
        atomicAdd(&acc[d + 6], b.z);
    }
    __syncthreads();
    int n = (bu << LOG_NB) + t;
    if (n >= N) return;
    const float4* ps = (const float4*)(xd + (size_t)n * 8);
    float4 sa = ps[0], sb = ps[1];
    float di = sb.w;  // dinv packed in slot 7
    float ax[7];
    ax[0] = acc[t * APAD + 0] + sa.x; ax[1] = acc[t * APAD + 1] + sa.y;
    ax[2] = acc[t * APAD + 2] + sa.z; ax[3] = acc[t * APAD + 3] + sa.w;
    ax[4] = acc[t * APAD + 4] + sb.x; ax[5] = acc[t * APAD + 5] + sb.y;
    ax[6] = acc[t * APAD + 6] + sb.z;
    float y = 0.f;
#pragma unroll
    for (int ff = 0; ff < 16; ++ff) {
        float h = 0.f;
#pragma unroll
        for (int k = 0; k < 7; ++k) h = fmaf(ax[k], sW1[k * 16 + ff], h);
        h = fmaxf(di * h + sb1[ff], 0.f);
        y = fmaf(h, sw2[ff], y);
    }
    g2[n] = di * y;
}

// ---- 7) per-bucket layer-2 aggregation + fused mean-pool binning ----
__global__ __launch_bounds__(TPB) void acc2_pool_kernel(const int* __restrict__ ptr,
                                                        const int* __restrict__ bpack,
                                                        const float* __restrict__ g2,
                                                        const float* __restrict__ xd,
                                                        const float* __restrict__ b2,
                                                        const int* __restrict__ batch,
                                                        float* __restrict__ sums,
                                                        float* __restrict__ cnts, int N) {
    __shared__ float acc[NBNODES];
    __shared__ float ssum[64], scnt[64];
    int t = threadIdx.x;
    acc[t] = 0.f;
    if (t < 64) { ssum[t] = 0.f; scnt[t] = 0.f; }
    __syncthreads();
    int bu = blockIdx.x;
    int beg = ptr[bu], end = ptr[bu + 1];
    int e = beg + t;
    for (; e + 3 * TPB < end; e += 4 * TPB) {  // 4x unroll
        int v0 = bpack[e];
        int v1 = bpack[e + TPB];
        int v2 = bpack[e + 2 * TPB];
        int v3 = bpack[e + 3 * TPB];
        float a0 = g2[v0 >> LOG_NB];
        float a1 = g2[v1 >> LOG_NB];
        float a2 = g2[v2 >> LOG_NB];
        float a3 = g2[v3 >> LOG_NB];
        atomicAdd(&acc[v0 & (NBNODES - 1)], a0);
        atomicAdd(&acc[v1 & (NBNODES - 1)], a1);
        atomicAdd(&acc[v2 & (NBNODES - 1)], a2);
        atomicAdd(&acc[v3 & (NBNODES - 1)], a3);
    }
    for (; e < end; e += TPB) {
        int v = bpack[e];
        atomicAdd(&acc[v & (NBNODES - 1)], g2[v >> LOG_NB]);
    }
    __syncthreads();
    int n = (bu << LOG_NB) + t;
    if (n < N) {
        float di = xd[(size_t)n * 8 + 7];
        float h2 = di * (acc[t] + g2[n]) + b2[0];
        int g = batch[n];
        atomicAdd(&ssum[g], h2);
        atomicAdd(&scnt[g], 1.0f);
    }
    __syncthreads();
    if (t < 64 && scnt[t] != 0.f) {
        atomicAdd(&sums[t], ssum[t]);
        atomicAdd(&cnts[t], scnt[t]);
    }
}

__global__ void finalize_kernel(const float* __restrict__ sums, const float* __restrict__ cnts,
                                float* __restrict__ out, int G) {
    int g = blockIdx.x * blockDim.x + threadIdx.x;
    if (g < G) {
        float m = sums[g] / fmaxf(cnts[g], 1.0f);
        out[g] = 1.0f / (1.0f + expf(-m));
    }
}

extern "C" void kernel_launch(void* const* d_in, const int* in_sizes, int n_in,
                              void* d_out, int out_size, void* d_ws, size_t ws_size,
                              hipStream_t stream) {
    const float* x  = (const float*)d_in[0];
    const float* W1 = (const float*)d_in[1];
    const float* b1 = (const float*)d_in[2];
    const float* W2 = (const float*)d_in[3];
    const float* b2 = (const float*)d_in[4];
    const int* ei   = (const int*)d_in[5];
    const int* batch = (const int*)d_in[6];

    const int N = in_sizes[0] / 7;   // 500000 (< 2^23, required for packing)
    const int E = in_sizes[5] / 2;   // 8000000
    const int G = out_size;          // 64
    const int* src = ei;
    const int* dst = ei + E;
    const int nbuck = (N + NBNODES - 1) >> LOG_NB;  // 1954
    const int nchunk = (E + CHUNK - 1) / CHUNK;     // 245

    char* ws = (char*)d_ws;
    size_t off = 0;
    auto walloc = [&](size_t bytes) -> void* {
        void* p = ws + off;
        off += (bytes + 255) & ~(size_t)255;
        return p;
    };
    int*   bucket_cnt = (int*)  walloc((size_t)MAXBUCK * 4);
    int*   ptr        = (int*)  walloc((size_t)(MAXBUCK + 1) * 4);
    int*   gcursor    = (int*)  walloc((size_t)MAXBUCK * 4);
    float* dinv       = (float*)walloc((size_t)N * 4);
    float* xd         = (float*)walloc((size_t)N * 8 * 4);
    int*   bpack      = (int*)  walloc((size_t)E * 4);
    float* g2         = (float*)walloc((size_t)N * 4);
    float* sums       = (float*)walloc(64 * 4);
    float* cnts       = (float*)walloc(64 * 4);

    hipMemsetAsync(bucket_cnt, 0, (size_t)MAXBUCK * 4, stream);
    hipMemsetAsync(sums, 0, 64 * 4, stream);
    hipMemsetAsync(cnts, 0, 64 * 4, stream);

    bucket_count_kernel<<<512, TPB, 0, stream>>>(dst, E, nbuck, bucket_cnt);
    bucket_scan_kernel<<<1, 1024, 0, stream>>>(bucket_cnt, nbuck, ptr);
    hipMemcpyAsync(gcursor, ptr, (size_t)nbuck * 4, hipMemcpyDeviceToDevice, stream);
    bucket_scatter_kernel<<<nchunk, TPB, 0, stream>>>(src, dst, E, nbuck, gcursor, bpack);

    dinv_kernel<<<nbuck, TPB, 0, stream>>>(ptr, bpack, dinv, N);
    xd_prep_kernel<<<(N + TPB - 1) / TPB, TPB, 0, stream>>>(x, dinv, xd, N);
    acc1_kernel<<<nbuck, TPB, 0, stream>>>(ptr, bpack, xd, W1, b1, W2, g2, N);
    acc2_pool_kernel<<<nbuck, TPB, 0, stream>>>(ptr, bpack, g2, xd, b2, batch, sums, cnts, N);
    finalize_kernel<<<1, 64, 0, stream>>>(sums, cnts, (float*)d_out, G);
}